// Round 2
// baseline (1787.140 us; speedup 1.0000x reference)
//
#include <hip/hip_runtime.h>
#include <math.h>

#define NTHREADS 1024

namespace {
constexpr int kB = 8, kS = 96, kIN = 128, kH = 2, kM = 32, kN = 512;
constexpr int kSTATE = 256, kOUT = 126, kCIN = 448, kUH = 106;
constexpr int kMLD = 520;           // padded mem row stride (8m bank offset)
constexpr float kEPS = 1e-12f;
}

__device__ __forceinline__ float sigm_(float x) { return 1.0f / (1.0f + expf(-x)); }
__device__ __forceinline__ float splus_(float x) { return x > 20.0f ? x : log1pf(expf(x)); }

__global__ __launch_bounds__(NTHREADS) void dwm_kernel(
    const float* __restrict__ x,
    const float* __restrict__ Ws, const float* __restrict__ bs,
    const float* __restrict__ Wo, const float* __restrict__ bo,
    const float* __restrict__ Wu, const float* __restrict__ bu,
    float* __restrict__ out)
{
    __shared__ float s_mem[kM * kMLD];     // 66.6 KB memory matrix [M][N] (padded)
    __shared__ float s_wt[kH * kN];        // current address weights
    __shared__ float s_wtd[kH * kN];       // bookmark weights
    __shared__ float s_tmp[kH * kN];       // scores -> wt_c scratch
    __shared__ float s_comb[kCIN];
    __shared__ float s_state[kSTATE];
    __shared__ float s_upd[kH * kUH];
    __shared__ float s_er[kH * kM], s_ad[kH * kM], s_kk[kH * kM];
    __shared__ float s_red[16];
    __shared__ float s_shift[kH][3], s_jmp[kH][3];
    __shared__ float s_jd[kH], s_gam[kH], s_beta[kH], s_g[kH], s_ikn[kH];
    __shared__ float s_mx[kH], s_sum[kH];

    const int b = blockIdx.x;
    const int t = threadIdx.x;
    const int wid = t >> 6;
    const int lane = t & 63;

    // ---- initial carry ----
    for (int i = t; i < kM * kN; i += NTHREADS)
        s_mem[(i >> 9) * kMLD + (i & 511)] = 0.01f;
    for (int i = t; i < kH * kN; i += NTHREADS) {
        float v = ((i & 511) == 0) ? 1.0f : 0.0f;
        s_wt[i] = v; s_wtd[i] = v;
    }
    if (t < kSTATE) s_state[t] = 1.0f;
    __syncthreads();

    for (int step = 0; step < kS; ++step) {
        // ---- P0: read[h,m] = sum_n wt[h,n]*mem[m,n]; assemble comb ----
        {
            int g = t >> 4, l16 = t & 15;      // 64 groups of 16
            int h = g >> 5, m = g & 31;
            const float* wrow = &s_wt[h * kN];
            const float* mrow = &s_mem[m * kMLD];
            float acc = 0.0f;
            #pragma unroll
            for (int k = 0; k < 32; ++k) {
                int n = l16 + (k << 4);
                acc += wrow[n] * mrow[n];
            }
            acc += __shfl_xor(acc, 1);
            acc += __shfl_xor(acc, 2);
            acc += __shfl_xor(acc, 4);
            acc += __shfl_xor(acc, 8);
            if (l16 == 0) s_comb[kIN + g] = acc;
            if (t < kIN) s_comb[t] = x[(b * kS + step) * kIN + t];
            if (t >= kIN && t < kIN + kSTATE)
                s_comb[kIN + kH * kM + (t - kIN)] = s_state[t - kIN];
        }
        __syncthreads();

        // ---- P1: GEMV comb @ [Ws | Wo | Wu] (one column per thread) ----
        if (t < 594) {
            const float* Wp; int ld, j; float acc;
            if (t < 256)      { Wp = Ws; ld = kSTATE;     j = t;       acc = bs[j]; }
            else if (t < 382) { Wp = Wo; ld = kOUT;       j = t - 256; acc = bo[j]; }
            else              { Wp = Wu; ld = kH * kUH;   j = t - 382; acc = bu[j]; }
            const float* p = Wp + j;
            #pragma unroll 8
            for (int i = 0; i < kCIN; ++i) acc += s_comb[i] * p[i * ld];
            if (t < 256)      s_state[j] = sigm_(acc);
            else if (t < 382) out[(b * kS + step) * kOUT + j] = acc;
            else              s_upd[j] = acc;
        }
        __syncthreads();

        // ---- P2: interface activations ----
        if (t < 64) {
            int h = t >> 5, m = t & 31;
            const float* u = &s_upd[h * kUH];
            s_er[t] = sigm_(u[8 + m]);
            s_ad[t] = u[40 + m];
            float kv = tanhf(u[72 + m]);
            s_kk[t] = kv;
            float ss = kv * kv;
            ss += __shfl_xor(ss, 1);
            ss += __shfl_xor(ss, 2);
            ss += __shfl_xor(ss, 4);
            ss += __shfl_xor(ss, 8);
            ss += __shfl_xor(ss, 16);
            if (m == 0) s_ikn[h] = 1.0f / (sqrtf(ss) + kEPS);
        } else if (t == 64 || t == 65) {
            int h = t - 64;
            const float* u = &s_upd[h * kUH];
            float a0 = splus_(u[0]), a1 = splus_(u[1]), a2 = splus_(u[2]);
            float mx = fmaxf(a0, fmaxf(a1, a2));
            float e0 = expf(a0 - mx), e1 = expf(a1 - mx), e2 = expf(a2 - mx);
            float inv = 1.0f / (e0 + e1 + e2);
            s_shift[h][0] = e0 * inv; s_shift[h][1] = e1 * inv; s_shift[h][2] = e2 * inv;
            s_jd[h] = sigm_(u[3]);
            a0 = u[4]; a1 = u[5]; a2 = u[6];
            mx = fmaxf(a0, fmaxf(a1, a2));
            e0 = expf(a0 - mx); e1 = expf(a1 - mx); e2 = expf(a2 - mx);
            inv = 1.0f / (e0 + e1 + e2);
            s_jmp[h][0] = e0 * inv; s_jmp[h][1] = e1 * inv; s_jmp[h][2] = e2 * inv;
            s_gam[h]  = 1.0f + splus_(u[7]);
            s_beta[h] = splus_(u[104]);
            s_g[h]    = sigm_(u[105]);
        }
        __syncthreads();

        // ---- P3: memory erase then add (uses OLD wt) ----
        #pragma unroll
        for (int q = 0; q < (kM * kN) / NTHREADS; ++q) {
            int idx = t + q * NTHREADS;
            int m = idx >> 9, n = idx & 511;
            float w0 = s_wt[n], w1 = s_wt[kN + n];
            float v = s_mem[m * kMLD + n];
            v = v * (1.0f - s_er[m] * w0) * (1.0f - s_er[kM + m] * w1)
              + s_ad[m] * w0 + s_ad[kM + m] * w1;
            s_mem[m * kMLD + n] = v;
        }
        __syncthreads();

        // ---- P4: content scores beta * cos-sim (fused column norm) ----
        if (t < kN) {
            int n = t;
            float a0 = 0.0f, a1 = 0.0f, ss = 0.0f;
            #pragma unroll
            for (int m = 0; m < kM; ++m) {
                float v = s_mem[m * kMLD + n];
                a0 += s_kk[m] * v;
                a1 += s_kk[kM + m] * v;
                ss += v * v;
            }
            float invc = 1.0f / (sqrtf(ss) + kEPS);
            s_tmp[n]      = s_beta[0] * (a0 * s_ikn[0] * invc);
            s_tmp[kN + n] = s_beta[1] * (a1 * s_ikn[1] * invc);
        }
        __syncthreads();

        // ---- P5: softmax over n (per head) + gate with old wt -> wt_c ----
        {
            int h = t >> 9;
            float v = s_tmp[t];
            float mx = v;
            mx = fmaxf(mx, __shfl_xor(mx, 1));
            mx = fmaxf(mx, __shfl_xor(mx, 2));
            mx = fmaxf(mx, __shfl_xor(mx, 4));
            mx = fmaxf(mx, __shfl_xor(mx, 8));
            mx = fmaxf(mx, __shfl_xor(mx, 16));
            mx = fmaxf(mx, __shfl_xor(mx, 32));
            if (lane == 0) s_red[wid] = mx;
            __syncthreads();
            if (t < 2) {
                float m2 = s_red[t * 8];
                #pragma unroll
                for (int i = 1; i < 8; ++i) m2 = fmaxf(m2, s_red[t * 8 + i]);
                s_mx[t] = m2;
            }
            __syncthreads();
            float e = expf(v - s_mx[h]);
            float sm = e;
            sm += __shfl_xor(sm, 1);
            sm += __shfl_xor(sm, 2);
            sm += __shfl_xor(sm, 4);
            sm += __shfl_xor(sm, 8);
            sm += __shfl_xor(sm, 16);
            sm += __shfl_xor(sm, 32);
            if (lane == 0) s_red[wid] = sm;
            __syncthreads();
            if (t < 2) {
                float m2 = 0.0f;
                #pragma unroll
                for (int i = 0; i < 8; ++i) m2 += s_red[t * 8 + i];
                s_sum[t] = m2;
            }
            __syncthreads();
            float wc = s_g[h] * e / s_sum[h] + (1.0f - s_g[h]) * s_wt[t];
            s_tmp[t] = wc;
        }
        __syncthreads();

        // ---- P6: circular conv + sharpen (+ sum reduce) ----
        float wsh;
        {
            int h = t >> 9, n = t & 511;
            const float* wcp = &s_tmp[h * kN];
            float cv = s_shift[h][0] * wcp[(n + 1) & 511]
                     + s_shift[h][1] * wcp[n]
                     + s_shift[h][2] * wcp[(n + 511) & 511];
            wsh = powf(cv + kEPS, s_gam[h]);
            float sm = wsh;
            sm += __shfl_xor(sm, 1);
            sm += __shfl_xor(sm, 2);
            sm += __shfl_xor(sm, 4);
            sm += __shfl_xor(sm, 8);
            sm += __shfl_xor(sm, 16);
            sm += __shfl_xor(sm, 32);
            if (lane == 0) s_red[wid] = sm;
        }
        __syncthreads();
        if (t < 2) {
            float m2 = 0.0f;
            #pragma unroll
            for (int i = 0; i < 8; ++i) m2 += s_red[t * 8 + i];
            s_sum[t] = m2;
        }
        __syncthreads();

        // ---- P7: normalize + bookmark update + jump interpolation ----
        {
            int h = t >> 9, n = t & 511;
            float wn = wsh / s_sum[h];
            float dold = s_wtd[t];
            s_wtd[t] = (1.0f - s_jd[h]) * dold + s_jd[h] * wn;
            float wa0 = (n == 0) ? 1.0f : 0.0f;
            s_wt[t] = s_jmp[h][0] * wn + s_jmp[h][1] * wa0 + s_jmp[h][2] * dold;
        }
        __syncthreads();
    }
}

extern "C" void kernel_launch(void* const* d_in, const int* in_sizes, int n_in,
                              void* d_out, int out_size, void* d_ws, size_t ws_size,
                              hipStream_t stream) {
    const float* x   = (const float*)d_in[0];
    const float* Ws  = (const float*)d_in[1];
    const float* bs  = (const float*)d_in[2];
    const float* Wo  = (const float*)d_in[3];
    const float* bo  = (const float*)d_in[4];
    const float* Wu  = (const float*)d_in[5];
    const float* bu  = (const float*)d_in[6];
    float* outp = (float*)d_out;
    dwm_kernel<<<dim3(kB), dim3(NTHREADS), 0, stream>>>(x, Ws, bs, Wo, bo, Wu, bu, outp);
}